// Round 2
// baseline (119.541 us; speedup 1.0000x reference)
//
#include <hip/hip_runtime.h>

// AR(p) self-feeding recurrence.
// Reference: h0 = last P timesteps of x per (b,n); then T steps of
//   pred = a_n . h + bias_n ; h = shift(h, pred)
// Output: (B, T, N, 1) fp32, flat index b*T*N + t*N + n.

constexpr int B = 64;
constexpr int T = 288;
constexpr int N = 1024;
constexpr int P = 12;

__global__ __launch_bounds__(256) void ar_model_kernel(
    const float* __restrict__ x,        // (B, T, N, 1)
    const float* __restrict__ ar,       // (N, P)
    const float* __restrict__ bias,     // (N,)
    float* __restrict__ out)            // (B, T, N, 1)
{
    const int tid = blockIdx.x * blockDim.x + threadIdx.x;
    const int n = tid & (N - 1);
    const int b = tid >> 10;            // N == 1024
    if (b >= B) return;

    // Per-node AR coefficients (12 contiguous floats per n).
    float a[P];
    const float* arow = ar + n * P;
#pragma unroll
    for (int j = 0; j < P; ++j) a[j] = arow[j];
    const float bs = bias[n];

    // Initial history: x[b, T-P+j, n, 0], j = 0..P-1 (h[0] oldest).
    float h[P];
    const float* xb = x + (size_t)b * T * N + (size_t)(T - P) * N + n;
#pragma unroll
    for (int j = 0; j < P; ++j) h[j] = xb[(size_t)j * N];

    float* ob = out + (size_t)b * T * N + n;

    // Circular register buffer: at step t, logical element j lives in
    // h[(t + j) % P]; the oldest (h[t % P]) is overwritten by the new pred.
    // T = 288 = 24 * 12, so with the inner 12-step loop fully unrolled all
    // indices are compile-time constants (pure register renaming).
#pragma unroll 1
    for (int tt = 0; tt < T; tt += P) {
#pragma unroll
        for (int k = 0; k < P; ++k) {
            float pred = bs;
#pragma unroll
            for (int j = 0; j < P; ++j)
                pred = fmaf(a[j], h[(k + j) % P], pred);
            h[k % P] = pred;                       // drop oldest, append newest
            ob[(size_t)(tt + k) * N] = pred;       // coalesced 256B/wave store
        }
    }
}

extern "C" void kernel_launch(void* const* d_in, const int* in_sizes, int n_in,
                              void* d_out, int out_size, void* d_ws, size_t ws_size,
                              hipStream_t stream) {
    const float* x    = (const float*)d_in[0];   // (B,T,N,1) fp32
    const float* ar   = (const float*)d_in[1];   // (N,P) fp32
    const float* bias = (const float*)d_in[2];   // (N,) fp32
    float* out = (float*)d_out;                  // (B,T,N,1) fp32

    const int total = B * N;                     // one thread per (b, n)
    const int block = 256;
    const int grid = (total + block - 1) / block;
    ar_model_kernel<<<grid, block, 0, stream>>>(x, ar, bias, out);
}

// Round 3
// 118.551 us; speedup vs baseline: 1.0083x; 1.0083x over previous
//
#include <hip/hip_runtime.h>

// AR(p) self-feeding recurrence, scatter form.
// pred_t = bias + sum_j a_j * v_{t-12+j}, v_k = history (k<0) or pred_k.
// Instead of a 12-deep dependent FMA chain per step (gather), each produced
// value scatter-adds into the 12 future accumulators -> critical path is
// 1 FMA/step; the other 11 FMAs are independent and pipeline freely.
// Accumulation order per output (bias first, then j ascending) is identical
// to the gather version -> bitwise-comparable numerics.

constexpr int B = 64;
constexpr int T = 288;
constexpr int N = 1024;
constexpr int P = 12;

__global__ __launch_bounds__(256) void ar_model_kernel(
    const float* __restrict__ x,        // (B, T, N, 1)
    const float* __restrict__ ar,       // (N, P)
    const float* __restrict__ bias,     // (N,)
    float* __restrict__ out)            // (B, T, N, 1)
{
    const int tid = blockIdx.x * blockDim.x + threadIdx.x;
    const int n = tid & (N - 1);
    const int b = tid >> 10;            // N == 1024
    if (b >= B) return;

    // Per-node AR coefficients (12 contiguous floats per n).
    float a[P];
    const float* arow = ar + n * P;
#pragma unroll
    for (int j = 0; j < P; ++j) a[j] = arow[j];
    const float bs = bias[n];

    // acc[t % P] accumulates pred_t's dot product. Init with bias, then
    // scatter the history window x[b, T-P+i, n] (i=0..11, oldest first):
    // h_i contributes a_{i-t} * h_i to pred_t for t = 0..i (triangular).
    float acc[P];
#pragma unroll
    for (int s = 0; s < P; ++s) acc[s] = bs;

    const float* xb = x + (size_t)b * T * N + (size_t)(T - P) * N + n;
#pragma unroll
    for (int i = 0; i < P; ++i) {
        const float hv = xb[(size_t)i * N];
#pragma unroll
        for (int t = 0; t <= i; ++t)
            acc[t] = fmaf(a[i - t], hv, acc[t]);
    }

    float* ob = out + (size_t)b * T * N + n;

    // Main loop: T = 288 = 24 * 12; inner 12 steps fully unrolled so all
    // acc indices are compile-time constants (registers, no scratch).
    // Per step: read completed acc[k] -> store -> reset slot for pred_{t+12}
    // (coeff a_0) -> scatter a_{P-d} * pred into the 11 other future slots.
#pragma unroll 1
    for (int tt = 0; tt < T; tt += P) {
#pragma unroll
        for (int k = 0; k < P; ++k) {
            const float pred = acc[k];
            ob[(size_t)(tt + k) * N] = pred;       // coalesced 256B/wave store
            acc[k] = fmaf(a[0], pred, bs);         // slot now serves pred_{t+12}
#pragma unroll
            for (int d = 1; d < P; ++d)
                acc[(k + d) % P] = fmaf(a[P - d], pred, acc[(k + d) % P]);
        }
    }
}

extern "C" void kernel_launch(void* const* d_in, const int* in_sizes, int n_in,
                              void* d_out, int out_size, void* d_ws, size_t ws_size,
                              hipStream_t stream) {
    const float* x    = (const float*)d_in[0];   // (B,T,N,1) fp32
    const float* ar   = (const float*)d_in[1];   // (N,P) fp32
    const float* bias = (const float*)d_in[2];   // (N,) fp32
    float* out = (float*)d_out;                  // (B,T,N,1) fp32

    const int total = B * N;                     // one thread per (b, n)
    const int block = 256;
    const int grid = (total + block - 1) / block;
    ar_model_kernel<<<grid, block, 0, stream>>>(x, ar, bias, out);
}